// Round 4
// baseline (430.848 us; speedup 1.0000x reference)
//
#include <hip/hip_runtime.h>

// ---------- types ----------
typedef __attribute__((ext_vector_type(8))) short bfrag8;   // 8 bf16 bit patterns (4 VGPRs)
typedef __attribute__((ext_vector_type(4))) short bfrag4;
typedef __attribute__((ext_vector_type(4))) float f32x4;
typedef __attribute__((ext_vector_type(4))) int   i32x4;

// ---------- bf16 helpers ----------
__device__ __forceinline__ float bf2f(unsigned short h){
  unsigned u = ((unsigned)h) << 16;
  return __builtin_bit_cast(float, u);
}
__device__ __forceinline__ unsigned short f2bf(float f){
  unsigned u = __builtin_bit_cast(unsigned, f);
  u = u + 0x7FFFu + ((u >> 16) & 1u);        // round-to-nearest-even
  return (unsigned short)(u >> 16);
}
__device__ __forceinline__ bfrag8 gload8(const unsigned short* p){ // 16B-aligned global, bf16
  int4 v = *(const int4*)p;
  return __builtin_bit_cast(bfrag8, v);
}
__device__ __forceinline__ bfrag8 neg8(bfrag8 x){                  // packed bf16 sign flip
  i32x4 u = __builtin_bit_cast(i32x4, x);
#pragma unroll
  for (int i = 0; i < 4; i++) u[i] ^= 0x80008000;
  return __builtin_bit_cast(bfrag8, u);
}
__device__ __forceinline__ bfrag8 lds_load8(const unsigned short* p){ // 8B-aligned LDS
  bfrag4 lo = *(const bfrag4*)p;
  bfrag4 hi = *(const bfrag4*)(p + 4);
  bfrag8 r;
#pragma unroll
  for (int j = 0; j < 4; j++){ r[j] = lo[j]; r[4+j] = hi[j]; }
  return r;
}
__device__ __forceinline__ f32x4 mfma16(bfrag8 a, bfrag8 b, f32x4 c){
  return __builtin_amdgcn_mfma_f32_16x16x32_bf16(a, b, c, 0, 0, 0);
}

// ---------- dtype-dispatched accessors (flag: 1 = tensor is f32) ----------
__device__ __forceinline__ float ldf(const void* p, size_t i, int f32){
  return f32 ? ((const float*)p)[i] : bf2f(((const unsigned short*)p)[i]);
}
__device__ __forceinline__ unsigned short ldbf(const void* p, size_t i, int f32){
  return f32 ? f2bf(((const float*)p)[i]) : ((const unsigned short*)p)[i];
}
__device__ __forceinline__ bfrag8 load8bf(const void* p, size_t base, int f32){
  if (f32){
    const float* f = (const float*)p + base;
    float4 x = *(const float4*)f;
    float4 y = *(const float4*)(f + 4);
    bfrag8 r;
    r[0]=(short)f2bf(x.x); r[1]=(short)f2bf(x.y); r[2]=(short)f2bf(x.z); r[3]=(short)f2bf(x.w);
    r[4]=(short)f2bf(y.x); r[5]=(short)f2bf(y.y); r[6]=(short)f2bf(y.z); r[7]=(short)f2bf(y.w);
    return r;
  }
  return gload8((const unsigned short*)p + base);
}

// ---------- reductions ----------
// row16 all-reduce on the VALU pipe (DPP), keeping the DS pipe free.
// xor1, xor2 (quad_perm), then mirrors: valid because after each stage all
// lanes of the sub-group hold the same partial sum.
template<int CTRL>
__device__ __forceinline__ float dpp_add(float x){
  int xi = __builtin_bit_cast(int, x);
  int yi = __builtin_amdgcn_update_dpp(0, xi, CTRL, 0xF, 0xF, true);
  return x + __builtin_bit_cast(float, yi);
}
__device__ __forceinline__ float row16_sum(float x){
  x = dpp_add<0xB1>(x);    // quad_perm [1,0,3,2]  : + lane^1
  x = dpp_add<0x4E>(x);    // quad_perm [2,3,0,1]  : + lane^2
  x = dpp_add<0x141>(x);   // row_half_mirror      : + other quad
  x = dpp_add<0x140>(x);   // row_mirror           : + other 8-group
  return x;
}
__device__ __forceinline__ float xgrp_sum(float x){
  x += __shfl_xor(x, 16, 64);
  x += __shfl_xor(x, 32, 64);
  return x;
}
__device__ __forceinline__ float xgrp_max(float x){
  x = fmaxf(x, __shfl_xor(x, 16, 64));
  x = fmaxf(x, __shfl_xor(x, 32, 64));
  return x;
}

// ============================================================================
// Kernel 0: dtype sniffing + param canonicalization (merged).
// Weights -> fragment-ordered bf16; biases/scales -> f32; flags -> global.
// ============================================================================
struct Ptrs { const void* p[21]; int n[21]; };
struct PrepPtrs { const void* w[6]; const void* wp; const void* b[11]; };

__device__ int classify_f32(const unsigned short* p, int n){
  int m = n < 128 ? n : 128;
  int insane = 0, evenZero = 0, evenCnt = 0, oddNZ = 0, oddCnt = 0;
  for (int i = 0; i < m; i++){
    unsigned short h = p[i];
    int e = (h >> 7) & 0xFF;
    bool z = (h & 0x7FFF) == 0;
    if (!z && (e == 0xFF || e < 90 || e > 140)) insane++;
    if (i & 1){ oddCnt++;  if (!z) oddNZ++; }
    else      { evenCnt++; if (z)  evenZero++; }
  }
  if (insane > 0) return 1;
  if (evenZero * 4 >= evenCnt * 3 && oddNZ * 4 >= oddCnt * 3) return 1;
  return 0;
}

__global__ void prep_kernel(Ptrs ptrs, PrepPtrs pp, int* __restrict__ flags,
                            unsigned short* __restrict__ wfrag,
                            unsigned short* __restrict__ wp_bf,
                            float* __restrict__ biases)
{
  __shared__ int sflags[24];
  const int tid = threadIdx.x;
  if (tid < 21){
    int f = (tid == 2) ? 0 : classify_f32((const unsigned short*)ptrs.p[tid], ptrs.n[tid]);
    sflags[tid] = f;
    flags[tid] = f;
  }
  __syncthreads();

  const int wflag[6] = {3,5,7,13,17,19};          // wq,wk,wv,wg1,wg2,wo
  for (int idx = tid; idx < 6*4096; idx += 256){
    int m = idx >> 12;
    int r = idx & 4095;          // ((ks*4+t)*64 + lane)*8 + j
    int j = r & 7;
    int lane = (r >> 3) & 63;
    int kt = r >> 9;
    int ks = kt >> 2, t = kt & 3;
    int o = lane >> 4, rl = lane & 15;
    int src = (ks*32 + o*8 + j)*64 + t*16 + rl;   // B[k][n] fragment element
    wfrag[idx] = ldbf(pp.w[m], src, sflags[wflag[m]]);
  }
  for (int i = tid; i < 192; i += 256) wp_bf[i] = ldbf(pp.wp, i, sflags[9]);
  const int bflag[11] = {4,6,8,10,11,12,14,15,16,18,20};
  for (int i = tid; i < 11*64; i += 256){
    int m = i >> 6;
    biases[i] = ldf(pp.b[m], i & 63, sflags[bflag[m]]);
  }
}

// ============================================================================
// Kernel 1: q,k,v = features @ {wq,wk,wv} + bias -> bf16 scratch.
// Grid-stride over 16-row tiles; weight fragments held in registers.
// ============================================================================
__global__ __launch_bounds__(256)
void qkv_kernel(const void* __restrict__ feat,
                const unsigned short* __restrict__ wfrag,
                const float* __restrict__ biases,
                unsigned short* __restrict__ q_ws, unsigned short* __restrict__ k_ws,
                unsigned short* __restrict__ v_ws, const int* __restrict__ flags, int N)
{
  const int F_feat = flags[1];
  const int lane = threadIdx.x & 63;
  const int wave = threadIdx.x >> 6;
  const int o = lane >> 4, rl = lane & 15;

  bfrag8 wqf[2][4], wkf[2][4], wvf[2][4];
#pragma unroll
  for (int ks = 0; ks < 2; ks++)
#pragma unroll
    for (int t = 0; t < 4; t++){
      int off = ((ks*4 + t)*64 + lane)*8;
      wqf[ks][t] = gload8(wfrag + off);
      wkf[ks][t] = gload8(wfrag + 4096 + off);
      wvf[ks][t] = gload8(wfrag + 8192 + off);
    }
  float bqC[4], bkC[4], bvC[4];
#pragma unroll
  for (int t = 0; t < 4; t++){
    bqC[t] = biases[0*64 + t*16 + rl];
    bkC[t] = biases[1*64 + t*16 + rl];
    bvC[t] = biases[2*64 + t*16 + rl];
  }

  const int ntiles = (N + 15) >> 4;
  for (int tile = blockIdx.x*4 + wave; tile < ntiles; tile += gridDim.x*4){
    const int n0 = tile * 16;
    int ar = n0 + rl; if (ar >= N) ar = N - 1;
    bfrag8 a[2];
#pragma unroll
    for (int ks = 0; ks < 2; ks++) a[ks] = load8bf(feat, (size_t)ar*64 + ks*32 + o*8, F_feat);

#pragma unroll
    for (int t = 0; t < 4; t++){
      f32x4 zq = {0.f,0.f,0.f,0.f}, zk = {0.f,0.f,0.f,0.f}, zv = {0.f,0.f,0.f,0.f};
#pragma unroll
      for (int ks = 0; ks < 2; ks++){
        zq = mfma16(a[ks], wqf[ks][t], zq);
        zk = mfma16(a[ks], wkf[ks][t], zk);
        zv = mfma16(a[ks], wvf[ks][t], zv);
      }
#pragma unroll
      for (int q = 0; q < 4; q++){
        size_t row = n0 + o*4 + q; int col = t*16 + rl;
        if ((int)row < N){
          q_ws[row*64 + col] = f2bf(zq[q] + bqC[t]);
          k_ws[row*64 + col] = f2bf(zk[q] + bkC[t]);
          v_ws[row*64 + col] = f2bf(zv[q] + bvC[t]);
        }
      }
    }
  }
}

// ============================================================================
// Kernel 2: fused point-transformer. One wave per point (64-thread blocks);
// K=16 neighbors are the M-dim of 16x16x32 bf16 MFMAs.
// attn_in = q - gk + p is distributed through GEMM1 as three MFMA chains.
// ============================================================================
__global__ __launch_bounds__(64, 4)
void pt_kernel(const void* __restrict__ points,
               const void* __restrict__ feat,
               const int* __restrict__ nidx,
               const unsigned short* __restrict__ q_ws,
               const unsigned short* __restrict__ k_ws,
               const unsigned short* __restrict__ v_ws,
               const unsigned short* __restrict__ wfrag,
               const unsigned short* __restrict__ wp_bf,
               const float* __restrict__ biases,
               const int* __restrict__ flags, void* __restrict__ out, int N)
{
  __shared__ unsigned short xbuf[16][68];   // C<->A layout bounce (stride 68)
  __shared__ unsigned short ybuf[64];

  const int F_pts = flags[0], F_feat = flags[1];
  const int lane = threadIdx.x & 63;
  const int o = lane >> 4, rl = lane & 15;

  // ---- per-wave constants ----
  bfrag8 wg1f[2][4], wg2f[2][4], wof[2][4];
#pragma unroll
  for (int ks = 0; ks < 2; ks++)
#pragma unroll
    for (int t = 0; t < 4; t++){
      int off = ((ks*4 + t)*64 + lane)*8;
      wg1f[ks][t] = gload8(wfrag + 3*4096 + off);
      wg2f[ks][t] = gload8(wfrag + 4*4096 + off);
      wof[ks][t]  = gload8(wfrag + 5*4096 + off);
    }
  bfrag8 wpf[4];
#pragma unroll
  for (int t = 0; t < 4; t++){
    bfrag8 a = {0,0,0,0,0,0,0,0};
    if (o == 0){
#pragma unroll
      for (int j = 0; j < 3; j++) a[j] = (short)wp_bf[j*64 + t*16 + rl];
    }
    wpf[t] = a;
  }
  float bpC[4], gpC[4], bePC[4], bg1C[4], ggC[4], beGC[4], bg2C[4], boC[4];
#pragma unroll
  for (int t = 0; t < 4; t++){
    int c = t*16 + rl;
    bpC[t]  = biases[3*64 + c];  gpC[t]  = biases[4*64 + c];  bePC[t] = biases[5*64 + c];
    bg1C[t] = biases[6*64 + c];  ggC[t]  = biases[7*64 + c];  beGC[t] = biases[8*64 + c];
    bg2C[t] = biases[9*64 + c];  boC[t]  = biases[10*64 + c];
  }

  for (int n = blockIdx.x; n < N; n += gridDim.x){
    const int jr = nidx[n*16 + rl];          // A-layout row m = rl
    int jq[4];
#pragma unroll
    for (int q = 0; q < 4; q++) jq[q] = nidx[n*16 + o*4 + q];   // C-layout rows

    unsigned short gvu[4][4];                 // gv C-layout: [row q][tile t]
#pragma unroll
    for (int q = 0; q < 4; q++)
#pragma unroll
      for (int t = 0; t < 4; t++) gvu[q][t] = v_ws[(size_t)jq[q]*64 + t*16 + rl];
    const float res = ldf(feat, (size_t)n*64 + lane, F_feat);
    float rel[3];
#pragma unroll
    for (int d = 0; d < 3; d++)
      rel[d] = ldf(points, (size_t)jr*3 + d, F_pts) - ldf(points, (size_t)n*3 + d, F_pts);
    bfrag8 qv[2], gkn[2];
#pragma unroll
    for (int ks = 0; ks < 2; ks++){
      qv[ks]  = gload8(q_ws + (size_t)n*64  + ks*32 + o*8);   // broadcast A rows
      gkn[ks] = neg8(gload8(k_ws + (size_t)jr*64 + ks*32 + o*8));
    }

    // ---- p = relu(LN(rel @ wp + bp)) via MFMA (K padded 3->32) ----
    bfrag8 ap = {0,0,0,0,0,0,0,0};
    if (o == 0){
#pragma unroll
      for (int d = 0; d < 3; d++) ap[d] = (short)f2bf(rel[d]);
    }
    f32x4 pacc[4];
#pragma unroll
    for (int t = 0; t < 4; t++){
      f32x4 z = {0.f,0.f,0.f,0.f};
      pacc[t] = mfma16(ap, wpf[t], z);
    }
    float p_val[4][4];                        // [t][q], C-layout
#pragma unroll
    for (int q = 0; q < 4; q++){
      float xv[4]; float s = 0.f, s2 = 0.f;
#pragma unroll
      for (int t = 0; t < 4; t++){ xv[t] = pacc[t][q] + bpC[t]; s += xv[t]; s2 += xv[t]*xv[t]; }
      s = row16_sum(s); s2 = row16_sum(s2);
      float mu = s * (1.f/64.f);
      float var = s2 * (1.f/64.f) - mu*mu;
      float rs = rsqrtf(var + 1e-5f);
#pragma unroll
      for (int t = 0; t < 4; t++){
        float v = (xv[t] - mu) * rs * gpC[t] + bePC[t];
        p_val[t][q] = fmaxf(v, 0.f);
      }
    }

    // ---- p: C->A via LDS; GEMM1 = (q - gk + p) @ wg1 as 3 MFMA chains ----
#pragma unroll
    for (int q = 0; q < 4; q++)
#pragma unroll
      for (int t = 0; t < 4; t++) xbuf[o*4 + q][t*16 + rl] = f2bf(p_val[t][q]);
    f32x4 hacc[4] = {{0.f,0.f,0.f,0.f},{0.f,0.f,0.f,0.f},{0.f,0.f,0.f,0.f},{0.f,0.f,0.f,0.f}};
#pragma unroll
    for (int ks = 0; ks < 2; ks++){
      bfrag8 pA = lds_load8(&xbuf[rl][ks*32 + o*8]);
#pragma unroll
      for (int t = 0; t < 4; t++){
        hacc[t] = mfma16(pA,      wg1f[ks][t], hacc[t]);
        hacc[t] = mfma16(qv[ks],  wg1f[ks][t], hacc[t]);
        hacc[t] = mfma16(gkn[ks], wg1f[ks][t], hacc[t]);
      }
    }

    // ---- LN + relu -> h ----
    float h_val[4][4];
#pragma unroll
    for (int q = 0; q < 4; q++){
      float xv[4]; float s = 0.f, s2 = 0.f;
#pragma unroll
      for (int t = 0; t < 4; t++){ xv[t] = hacc[t][q] + bg1C[t]; s += xv[t]; s2 += xv[t]*xv[t]; }
      s = row16_sum(s); s2 = row16_sum(s2);
      float mu = s * (1.f/64.f);
      float var = s2 * (1.f/64.f) - mu*mu;
      float rs = rsqrtf(var + 1e-5f);
#pragma unroll
      for (int t = 0; t < 4; t++){
        float v = (xv[t] - mu) * rs * ggC[t] + beGC[t];
        h_val[t][q] = fmaxf(v, 0.f);
      }
    }

    // ---- h: C->A; GEMM2 ----
#pragma unroll
    for (int q = 0; q < 4; q++)
#pragma unroll
      for (int t = 0; t < 4; t++) xbuf[o*4 + q][t*16 + rl] = f2bf(h_val[t][q]);
    f32x4 wacc[4] = {{0.f,0.f,0.f,0.f},{0.f,0.f,0.f,0.f},{0.f,0.f,0.f,0.f},{0.f,0.f,0.f,0.f}};
#pragma unroll
    for (int ks = 0; ks < 2; ks++){
      bfrag8 hf = lds_load8(&xbuf[rl][ks*32 + o*8]);
#pragma unroll
      for (int t = 0; t < 4; t++) wacc[t] = mfma16(hf, wg2f[ks][t], wacc[t]);
    }

    // ---- softmax over neighbors + weighted sum ----
    float y[4];
#pragma unroll
    for (int t = 0; t < 4; t++){
      float wv[4];
#pragma unroll
      for (int q = 0; q < 4; q++) wv[q] = wacc[t][q] + bg2C[t];
      float mx = fmaxf(fmaxf(wv[0], wv[1]), fmaxf(wv[2], wv[3]));
      mx = xgrp_max(mx);
      float se = 0.f, z = 0.f;
#pragma unroll
      for (int q = 0; q < 4; q++){
        float e = __expf(wv[q] - mx);
        se += e;
        z  += e * (bf2f(gvu[q][t]) + p_val[t][q]);
      }
      se = xgrp_sum(se); z = xgrp_sum(z);
      y[t] = z / se;
    }

    // ---- out = y @ wo + bo + residual ----
    if (o == 0){
#pragma unroll
      for (int t = 0; t < 4; t++) ybuf[t*16 + rl] = f2bf(y[t]);
    }
    f32x4 oacc[4] = {{0.f,0.f,0.f,0.f},{0.f,0.f,0.f,0.f},{0.f,0.f,0.f,0.f},{0.f,0.f,0.f,0.f}};
#pragma unroll
    for (int ks = 0; ks < 2; ks++){
      bfrag8 yf = lds_load8(&ybuf[ks*32 + o*8]);
#pragma unroll
      for (int t = 0; t < 4; t++) oacc[t] = mfma16(yf, wof[ks][t], oacc[t]);
    }

    float ov = 0.f;
#pragma unroll
    for (int t = 0; t < 4; t++) if (o == t) ov = oacc[t][0] + boC[t];
    float outv = ov + res;
    if (F_feat) ((float*)out)[(size_t)n*64 + lane] = outv;
    else ((unsigned short*)out)[(size_t)n*64 + lane] = f2bf(outv);
  }
}

// ============================================================================
extern "C" void kernel_launch(void* const* d_in, const int* in_sizes, int n_in,
                              void* d_out, int out_size, void* d_ws, size_t ws_size,
                              hipStream_t stream)
{
  const int N = in_sizes[1] / 64;

  unsigned short* q_ws = (unsigned short*)d_ws;
  unsigned short* k_ws = q_ws + (size_t)N * 64;
  unsigned short* v_ws = k_ws + (size_t)N * 64;
  char* base = (char*)d_ws + (size_t)3 * N * 64 * sizeof(unsigned short);
  int*            flags  = (int*)base;                            // 128 B
  unsigned short* wfrag  = (unsigned short*)(base + 256);         // 49152 B
  unsigned short* wp_bf  = (unsigned short*)(base + 256 + 49152); // 384 B (pad 512)
  float*          biases = (float*)(base + 256 + 49152 + 512);    // 2816 B

  Ptrs ptrs;
  for (int i = 0; i < 21; i++){ ptrs.p[i] = d_in[i]; ptrs.n[i] = in_sizes[i]; }
  PrepPtrs pp;
  pp.w[0] = d_in[3];  pp.w[1] = d_in[5];  pp.w[2] = d_in[7];
  pp.w[3] = d_in[13]; pp.w[4] = d_in[17]; pp.w[5] = d_in[19];
  pp.wp = d_in[9];
  pp.b[0] = d_in[4];  pp.b[1] = d_in[6];  pp.b[2] = d_in[8];  pp.b[3] = d_in[10];
  pp.b[4] = d_in[11]; pp.b[5] = d_in[12]; pp.b[6] = d_in[14]; pp.b[7] = d_in[15];
  pp.b[8] = d_in[16]; pp.b[9] = d_in[18]; pp.b[10] = d_in[20];
  prep_kernel<<<1, 256, 0, stream>>>(ptrs, pp, flags, wfrag, wp_bf, biases);

  qkv_kernel<<<512, 256, 0, stream>>>(d_in[1], wfrag, biases, q_ws, k_ws, v_ws, flags, N);
  pt_kernel<<<4096, 64, 0, stream>>>(d_in[0], d_in[1], (const int*)d_in[2], q_ws, k_ws, v_ws,
                                     wfrag, wp_bf, biases, flags, d_out, N);
}

// Round 5
// 238.374 us; speedup vs baseline: 1.8074x; 1.8074x over previous
//
#include <hip/hip_runtime.h>

// ---------- types ----------
typedef __attribute__((ext_vector_type(8))) short bfrag8;   // 8 bf16 bit patterns (4 VGPRs)
typedef __attribute__((ext_vector_type(4))) short bfrag4;
typedef __attribute__((ext_vector_type(4))) float f32x4;
typedef __attribute__((ext_vector_type(4))) int   i32x4;

// ---------- bf16 helpers ----------
__device__ __forceinline__ float bf2f(unsigned short h){
  unsigned u = ((unsigned)h) << 16;
  return __builtin_bit_cast(float, u);
}
__device__ __forceinline__ unsigned short f2bf(float f){
  unsigned u = __builtin_bit_cast(unsigned, f);
  u = u + 0x7FFFu + ((u >> 16) & 1u);        // round-to-nearest-even
  return (unsigned short)(u >> 16);
}
__device__ __forceinline__ bfrag8 gload8(const unsigned short* p){ // 16B-aligned global, bf16
  int4 v = *(const int4*)p;
  return __builtin_bit_cast(bfrag8, v);
}
__device__ __forceinline__ bfrag8 neg8(bfrag8 x){                  // packed bf16 sign flip
  i32x4 u = __builtin_bit_cast(i32x4, x);
#pragma unroll
  for (int i = 0; i < 4; i++) u[i] ^= 0x80008000;
  return __builtin_bit_cast(bfrag8, u);
}
__device__ __forceinline__ bfrag8 lds_load8(const unsigned short* p){ // 8B-aligned LDS
  bfrag4 lo = *(const bfrag4*)p;
  bfrag4 hi = *(const bfrag4*)(p + 4);
  bfrag8 r;
#pragma unroll
  for (int j = 0; j < 4; j++){ r[j] = lo[j]; r[4+j] = hi[j]; }
  return r;
}
__device__ __forceinline__ f32x4 mfma16(bfrag8 a, bfrag8 b, f32x4 c){
  return __builtin_amdgcn_mfma_f32_16x16x32_bf16(a, b, c, 0, 0, 0);
}

// ---------- dtype-dispatched accessors (flag: 1 = tensor is f32) ----------
__device__ __forceinline__ float ldf(const void* p, size_t i, int f32){
  return f32 ? ((const float*)p)[i] : bf2f(((const unsigned short*)p)[i]);
}
__device__ __forceinline__ unsigned short ldbf(const void* p, size_t i, int f32){
  return f32 ? f2bf(((const float*)p)[i]) : ((const unsigned short*)p)[i];
}
__device__ __forceinline__ bfrag8 load8bf(const void* p, size_t base, int f32){
  if (f32){
    const float* f = (const float*)p + base;
    float4 x = *(const float4*)f;
    float4 y = *(const float4*)(f + 4);
    bfrag8 r;
    r[0]=(short)f2bf(x.x); r[1]=(short)f2bf(x.y); r[2]=(short)f2bf(x.z); r[3]=(short)f2bf(x.w);
    r[4]=(short)f2bf(y.x); r[5]=(short)f2bf(y.y); r[6]=(short)f2bf(y.z); r[7]=(short)f2bf(y.w);
    return r;
  }
  return gload8((const unsigned short*)p + base);
}

// ---------- reductions ----------
// row16 all-reduce on the VALU pipe (DPP), keeping the DS pipe free.
template<int CTRL>
__device__ __forceinline__ float dpp_add(float x){
  int xi = __builtin_bit_cast(int, x);
  int yi = __builtin_amdgcn_update_dpp(0, xi, CTRL, 0xF, 0xF, true);
  return x + __builtin_bit_cast(float, yi);
}
__device__ __forceinline__ float row16_sum(float x){
  x = dpp_add<0xB1>(x);    // quad_perm [1,0,3,2]  : + lane^1
  x = dpp_add<0x4E>(x);    // quad_perm [2,3,0,1]  : + lane^2
  x = dpp_add<0x141>(x);   // row_half_mirror      : + other quad
  x = dpp_add<0x140>(x);   // row_mirror           : + other 8-group
  return x;
}
__device__ __forceinline__ float xgrp_sum(float x){
  x += __shfl_xor(x, 16, 64);
  x += __shfl_xor(x, 32, 64);
  return x;
}
__device__ __forceinline__ float xgrp_max(float x){
  x = fmaxf(x, __shfl_xor(x, 16, 64));
  x = fmaxf(x, __shfl_xor(x, 32, 64));
  return x;
}

// ============================================================================
// Kernel 0a: dtype sniffing (see round-1 notes).
// ============================================================================
struct Ptrs { const void* p[21]; int n[21]; };
struct PrepPtrs { const void* w[6]; const void* wp; const void* b[11]; };

__device__ int classify_f32(const unsigned short* p, int n){
  int m = n < 128 ? n : 128;
  int insane = 0, evenZero = 0, evenCnt = 0, oddNZ = 0, oddCnt = 0;
  for (int i = 0; i < m; i++){
    unsigned short h = p[i];
    int e = (h >> 7) & 0xFF;
    bool z = (h & 0x7FFF) == 0;
    if (!z && (e == 0xFF || e < 90 || e > 140)) insane++;
    if (i & 1){ oddCnt++;  if (!z) oddNZ++; }
    else      { evenCnt++; if (z)  evenZero++; }
  }
  if (insane > 0) return 1;
  if (evenZero * 4 >= evenCnt * 3 && oddNZ * 4 >= oddCnt * 3) return 1;
  return 0;
}

__global__ void detect_kernel(Ptrs ptrs, int* flags){
  int t = threadIdx.x;
  if (t >= 21) return;
  flags[t] = (t == 2) ? 0 : classify_f32((const unsigned short*)ptrs.p[t], ptrs.n[t]);
}

// ============================================================================
// Kernel 0b: canonicalize params (parallel, 32 blocks).
// Weights -> fragment-ordered bf16; biases/scales -> f32.
// ============================================================================
__global__ void prep_kernel(PrepPtrs pp, const int* __restrict__ flags,
                            unsigned short* __restrict__ wfrag,
                            unsigned short* __restrict__ wp_bf,
                            float* __restrict__ biases)
{
  const int gid = blockIdx.x * 256 + threadIdx.x;
  const int gstride = gridDim.x * 256;
  const int wflag[6] = {3,5,7,13,17,19};          // wq,wk,wv,wg1,wg2,wo
  for (int idx = gid; idx < 6*4096; idx += gstride){
    int m = idx >> 12;
    int r = idx & 4095;          // ((ks*4+t)*64 + lane)*8 + j
    int j = r & 7;
    int lane = (r >> 3) & 63;
    int kt = r >> 9;
    int ks = kt >> 2, t = kt & 3;
    int o = lane >> 4, rl = lane & 15;
    int src = (ks*32 + o*8 + j)*64 + t*16 + rl;   // B[k][n] fragment element
    wfrag[idx] = ldbf(pp.w[m], src, flags[wflag[m]]);
  }
  if (blockIdx.x == 0){
    for (int i = threadIdx.x; i < 192; i += 256) wp_bf[i] = ldbf(pp.wp, i, flags[9]);
    const int bflag[11] = {4,6,8,10,11,12,14,15,16,18,20};
    for (int i = threadIdx.x; i < 11*64; i += 256){
      int m = i >> 6;
      biases[i] = ldf(pp.b[m], i & 63, flags[bflag[m]]);
    }
  }
}

// ============================================================================
// Kernel 1: q,k,v = features @ {wq,wk,wv} + bias -> bf16 scratch.
// Grid-stride over 16-row tiles; weight fragments held in registers.
// ============================================================================
__global__ __launch_bounds__(256, 2)
void qkv_kernel(const void* __restrict__ feat,
                const unsigned short* __restrict__ wfrag,
                const float* __restrict__ biases,
                unsigned short* __restrict__ q_ws, unsigned short* __restrict__ k_ws,
                unsigned short* __restrict__ v_ws, const int* __restrict__ flags, int N)
{
  const int F_feat = flags[1];
  const int lane = threadIdx.x & 63;
  const int wave = threadIdx.x >> 6;
  const int o = lane >> 4, rl = lane & 15;

  bfrag8 wqf[2][4], wkf[2][4], wvf[2][4];
#pragma unroll
  for (int ks = 0; ks < 2; ks++)
#pragma unroll
    for (int t = 0; t < 4; t++){
      int off = ((ks*4 + t)*64 + lane)*8;
      wqf[ks][t] = gload8(wfrag + off);
      wkf[ks][t] = gload8(wfrag + 4096 + off);
      wvf[ks][t] = gload8(wfrag + 8192 + off);
    }
  float bqC[4], bkC[4], bvC[4];
#pragma unroll
  for (int t = 0; t < 4; t++){
    bqC[t] = biases[0*64 + t*16 + rl];
    bkC[t] = biases[1*64 + t*16 + rl];
    bvC[t] = biases[2*64 + t*16 + rl];
  }

  const int ntiles = (N + 15) >> 4;
  for (int tile = blockIdx.x*4 + wave; tile < ntiles; tile += gridDim.x*4){
    const int n0 = tile * 16;
    int ar = n0 + rl; if (ar >= N) ar = N - 1;
    bfrag8 a[2];
#pragma unroll
    for (int ks = 0; ks < 2; ks++) a[ks] = load8bf(feat, (size_t)ar*64 + ks*32 + o*8, F_feat);

#pragma unroll
    for (int t = 0; t < 4; t++){
      f32x4 zq = {0.f,0.f,0.f,0.f}, zk = {0.f,0.f,0.f,0.f}, zv = {0.f,0.f,0.f,0.f};
#pragma unroll
      for (int ks = 0; ks < 2; ks++){
        zq = mfma16(a[ks], wqf[ks][t], zq);
        zk = mfma16(a[ks], wkf[ks][t], zk);
        zv = mfma16(a[ks], wvf[ks][t], zv);
      }
#pragma unroll
      for (int q = 0; q < 4; q++){
        size_t row = n0 + o*4 + q; int col = t*16 + rl;
        if ((int)row < N){
          q_ws[row*64 + col] = f2bf(zq[q] + bqC[t]);
          k_ws[row*64 + col] = f2bf(zk[q] + bkC[t]);
          v_ws[row*64 + col] = f2bf(zv[q] + bvC[t]);
        }
      }
    }
  }
}

// ============================================================================
// Kernel 2: fused point-transformer. 256-thread blocks, one wave per point;
// K=16 neighbors are the M-dim of 16x16x32 bf16 MFMAs.
// attn_in = q - gk + p distributed through GEMM1 as three MFMA chains.
// NOTE: weight fragments live in VGPRs (~96) — do NOT tighten launch bounds
// below (256,2): round-4's (64,4) clamped VGPR to 64 and spilled ~1 GB/launch.
// ============================================================================
__global__ __launch_bounds__(256, 2)
void pt_kernel(const void* __restrict__ points,
               const void* __restrict__ feat,
               const int* __restrict__ nidx,
               const unsigned short* __restrict__ q_ws,
               const unsigned short* __restrict__ k_ws,
               const unsigned short* __restrict__ v_ws,
               const unsigned short* __restrict__ wfrag,
               const unsigned short* __restrict__ wp_bf,
               const float* __restrict__ biases,
               const int* __restrict__ flags, void* __restrict__ out, int N)
{
  __shared__ unsigned short xbuf[4][16][68];   // per-wave C<->A bounce (stride 68)
  __shared__ unsigned short ybuf[4][64];

  const int F_pts = flags[0], F_feat = flags[1];
  const int lane = threadIdx.x & 63;
  const int wave = threadIdx.x >> 6;
  const int o = lane >> 4, rl = lane & 15;

  // ---- per-wave constants ----
  bfrag8 wg1f[2][4], wg2f[2][4], wof[2][4];
#pragma unroll
  for (int ks = 0; ks < 2; ks++)
#pragma unroll
    for (int t = 0; t < 4; t++){
      int off = ((ks*4 + t)*64 + lane)*8;
      wg1f[ks][t] = gload8(wfrag + 3*4096 + off);
      wg2f[ks][t] = gload8(wfrag + 4*4096 + off);
      wof[ks][t]  = gload8(wfrag + 5*4096 + off);
    }
  bfrag8 wpf[4];
#pragma unroll
  for (int t = 0; t < 4; t++){
    bfrag8 a = {0,0,0,0,0,0,0,0};
    if (o == 0){
#pragma unroll
      for (int j = 0; j < 3; j++) a[j] = (short)wp_bf[j*64 + t*16 + rl];
    }
    wpf[t] = a;
  }
  float bpC[4], gpC[4], bePC[4], bg1C[4], ggC[4], beGC[4], bg2C[4], boC[4];
#pragma unroll
  for (int t = 0; t < 4; t++){
    int c = t*16 + rl;
    bpC[t]  = biases[3*64 + c];  gpC[t]  = biases[4*64 + c];  bePC[t] = biases[5*64 + c];
    bg1C[t] = biases[6*64 + c];  ggC[t]  = biases[7*64 + c];  beGC[t] = biases[8*64 + c];
    bg2C[t] = biases[9*64 + c];  boC[t]  = biases[10*64 + c];
  }

  const int wstride = gridDim.x * 4;
  for (int n = blockIdx.x*4 + wave; n < N; n += wstride){
    const int jr = nidx[n*16 + rl];          // A-layout row m = rl
    int jq[4];
#pragma unroll
    for (int q = 0; q < 4; q++) jq[q] = nidx[n*16 + o*4 + q];   // C-layout rows

    unsigned short gvu[4][4];                 // gv C-layout: [row q][tile t]
#pragma unroll
    for (int q = 0; q < 4; q++)
#pragma unroll
      for (int t = 0; t < 4; t++) gvu[q][t] = v_ws[(size_t)jq[q]*64 + t*16 + rl];
    const float res = ldf(feat, (size_t)n*64 + lane, F_feat);
    float rel[3];
#pragma unroll
    for (int d = 0; d < 3; d++)
      rel[d] = ldf(points, (size_t)jr*3 + d, F_pts) - ldf(points, (size_t)n*3 + d, F_pts);
    bfrag8 qv[2], gkn[2];
#pragma unroll
    for (int ks = 0; ks < 2; ks++){
      qv[ks]  = gload8(q_ws + (size_t)n*64  + ks*32 + o*8);   // broadcast A rows
      gkn[ks] = neg8(gload8(k_ws + (size_t)jr*64 + ks*32 + o*8));
    }

    // ---- p = relu(LN(rel @ wp + bp)) via MFMA (K padded 3->32) ----
    bfrag8 ap = {0,0,0,0,0,0,0,0};
    if (o == 0){
#pragma unroll
      for (int d = 0; d < 3; d++) ap[d] = (short)f2bf(rel[d]);
    }
    f32x4 pacc[4];
#pragma unroll
    for (int t = 0; t < 4; t++){
      f32x4 z = {0.f,0.f,0.f,0.f};
      pacc[t] = mfma16(ap, wpf[t], z);
    }
    float p_val[4][4];                        // [t][q], C-layout
#pragma unroll
    for (int q = 0; q < 4; q++){
      float xv[4]; float s = 0.f, s2 = 0.f;
#pragma unroll
      for (int t = 0; t < 4; t++){ xv[t] = pacc[t][q] + bpC[t]; s += xv[t]; s2 += xv[t]*xv[t]; }
      s = row16_sum(s); s2 = row16_sum(s2);
      float mu = s * (1.f/64.f);
      float var = s2 * (1.f/64.f) - mu*mu;
      float rs = rsqrtf(var + 1e-5f);
#pragma unroll
      for (int t = 0; t < 4; t++){
        float v = (xv[t] - mu) * rs * gpC[t] + bePC[t];
        p_val[t][q] = fmaxf(v, 0.f);
      }
    }

    // ---- p: C->A via LDS; GEMM1 = (q - gk + p) @ wg1 as 3 MFMA chains ----
#pragma unroll
    for (int q = 0; q < 4; q++)
#pragma unroll
      for (int t = 0; t < 4; t++) xbuf[wave][o*4 + q][t*16 + rl] = f2bf(p_val[t][q]);
    f32x4 hacc[4] = {{0.f,0.f,0.f,0.f},{0.f,0.f,0.f,0.f},{0.f,0.f,0.f,0.f},{0.f,0.f,0.f,0.f}};
#pragma unroll
    for (int ks = 0; ks < 2; ks++){
      bfrag8 pA = lds_load8(&xbuf[wave][rl][ks*32 + o*8]);
#pragma unroll
      for (int t = 0; t < 4; t++){
        hacc[t] = mfma16(pA,      wg1f[ks][t], hacc[t]);
        hacc[t] = mfma16(qv[ks],  wg1f[ks][t], hacc[t]);
        hacc[t] = mfma16(gkn[ks], wg1f[ks][t], hacc[t]);
      }
    }

    // ---- LN + relu -> h ----
    float h_val[4][4];
#pragma unroll
    for (int q = 0; q < 4; q++){
      float xv[4]; float s = 0.f, s2 = 0.f;
#pragma unroll
      for (int t = 0; t < 4; t++){ xv[t] = hacc[t][q] + bg1C[t]; s += xv[t]; s2 += xv[t]*xv[t]; }
      s = row16_sum(s); s2 = row16_sum(s2);
      float mu = s * (1.f/64.f);
      float var = s2 * (1.f/64.f) - mu*mu;
      float rs = rsqrtf(var + 1e-5f);
#pragma unroll
      for (int t = 0; t < 4; t++){
        float v = (xv[t] - mu) * rs * ggC[t] + beGC[t];
        h_val[t][q] = fmaxf(v, 0.f);
      }
    }

    // ---- h: C->A; GEMM2 ----
#pragma unroll
    for (int q = 0; q < 4; q++)
#pragma unroll
      for (int t = 0; t < 4; t++) xbuf[wave][o*4 + q][t*16 + rl] = f2bf(h_val[t][q]);
    f32x4 wacc[4] = {{0.f,0.f,0.f,0.f},{0.f,0.f,0.f,0.f},{0.f,0.f,0.f,0.f},{0.f,0.f,0.f,0.f}};
#pragma unroll
    for (int ks = 0; ks < 2; ks++){
      bfrag8 hf = lds_load8(&xbuf[wave][rl][ks*32 + o*8]);
#pragma unroll
      for (int t = 0; t < 4; t++) wacc[t] = mfma16(hf, wg2f[ks][t], wacc[t]);
    }

    // ---- softmax over neighbors + weighted sum ----
    float y[4];
#pragma unroll
    for (int t = 0; t < 4; t++){
      float wv[4];
#pragma unroll
      for (int q = 0; q < 4; q++) wv[q] = wacc[t][q] + bg2C[t];
      float mx = fmaxf(fmaxf(wv[0], wv[1]), fmaxf(wv[2], wv[3]));
      mx = xgrp_max(mx);
      float se = 0.f, z = 0.f;
#pragma unroll
      for (int q = 0; q < 4; q++){
        float e = __expf(wv[q] - mx);
        se += e;
        z  += e * (bf2f(gvu[q][t]) + p_val[t][q]);
      }
      se = xgrp_sum(se); z = xgrp_sum(z);
      y[t] = z / se;
    }

    // ---- out = y @ wo + bo + residual ----
    if (o == 0){
#pragma unroll
      for (int t = 0; t < 4; t++) ybuf[wave][t*16 + rl] = f2bf(y[t]);
    }
    f32x4 oacc[4] = {{0.f,0.f,0.f,0.f},{0.f,0.f,0.f,0.f},{0.f,0.f,0.f,0.f},{0.f,0.f,0.f,0.f}};
#pragma unroll
    for (int ks = 0; ks < 2; ks++){
      bfrag8 yf = lds_load8(&ybuf[wave][ks*32 + o*8]);
#pragma unroll
      for (int t = 0; t < 4; t++) oacc[t] = mfma16(yf, wof[ks][t], oacc[t]);
    }

    float ov = 0.f;
#pragma unroll
    for (int t = 0; t < 4; t++) if (o == t) ov = oacc[t][0] + boC[t];
    float outv = ov + res;
    if (F_feat) ((float*)out)[(size_t)n*64 + lane] = outv;
    else ((unsigned short*)out)[(size_t)n*64 + lane] = f2bf(outv);
  }
}

// ============================================================================
extern "C" void kernel_launch(void* const* d_in, const int* in_sizes, int n_in,
                              void* d_out, int out_size, void* d_ws, size_t ws_size,
                              hipStream_t stream)
{
  const int N = in_sizes[1] / 64;

  unsigned short* q_ws = (unsigned short*)d_ws;
  unsigned short* k_ws = q_ws + (size_t)N * 64;
  unsigned short* v_ws = k_ws + (size_t)N * 64;
  char* base = (char*)d_ws + (size_t)3 * N * 64 * sizeof(unsigned short);
  int*            flags  = (int*)base;                            // 128 B
  unsigned short* wfrag  = (unsigned short*)(base + 256);         // 49152 B
  unsigned short* wp_bf  = (unsigned short*)(base + 256 + 49152); // 384 B (pad 512)
  float*          biases = (float*)(base + 256 + 49152 + 512);    // 2816 B

  Ptrs ptrs;
  for (int i = 0; i < 21; i++){ ptrs.p[i] = d_in[i]; ptrs.n[i] = in_sizes[i]; }
  PrepPtrs pp;
  pp.w[0] = d_in[3];  pp.w[1] = d_in[5];  pp.w[2] = d_in[7];
  pp.w[3] = d_in[13]; pp.w[4] = d_in[17]; pp.w[5] = d_in[19];
  pp.wp = d_in[9];
  pp.b[0] = d_in[4];  pp.b[1] = d_in[6];  pp.b[2] = d_in[8];  pp.b[3] = d_in[10];
  pp.b[4] = d_in[11]; pp.b[5] = d_in[12]; pp.b[6] = d_in[14]; pp.b[7] = d_in[15];
  pp.b[8] = d_in[16]; pp.b[9] = d_in[18]; pp.b[10] = d_in[20];

  detect_kernel<<<1, 64, 0, stream>>>(ptrs, flags);
  prep_kernel<<<32, 256, 0, stream>>>(pp, flags, wfrag, wp_bf, biases);
  qkv_kernel<<<512, 256, 0, stream>>>(d_in[1], wfrag, biases, q_ws, k_ws, v_ws, flags, N);
  pt_kernel<<<1024, 256, 0, stream>>>(d_in[0], d_in[1], (const int*)d_in[2], q_ws, k_ws, v_ws,
                                      wfrag, wp_bf, biases, flags, d_out, N);
}

// Round 6
// 224.939 us; speedup vs baseline: 1.9154x; 1.0597x over previous
//
#include <hip/hip_runtime.h>

// ---------- types ----------
typedef __attribute__((ext_vector_type(8))) short bfrag8;   // 8 bf16 bit patterns (4 VGPRs)
typedef __attribute__((ext_vector_type(4))) short bfrag4;
typedef __attribute__((ext_vector_type(4))) float f32x4;

// ---------- bf16 helpers ----------
__device__ __forceinline__ float bf2f(unsigned short h){
  unsigned u = ((unsigned)h) << 16;
  return __builtin_bit_cast(float, u);
}
__device__ __forceinline__ unsigned short f2bf(float f){
  unsigned u = __builtin_bit_cast(unsigned, f);
  u = u + 0x7FFFu + ((u >> 16) & 1u);        // round-to-nearest-even
  return (unsigned short)(u >> 16);
}
__device__ __forceinline__ bfrag8 gload8(const unsigned short* p){ // 16B-aligned global, bf16
  int4 v = *(const int4*)p;
  return __builtin_bit_cast(bfrag8, v);
}
__device__ __forceinline__ bfrag8 lds_load8(const unsigned short* p){ // 8B-aligned LDS
  bfrag4 lo = *(const bfrag4*)p;
  bfrag4 hi = *(const bfrag4*)(p + 4);
  bfrag8 r;
#pragma unroll
  for (int j = 0; j < 4; j++){ r[j] = lo[j]; r[4+j] = hi[j]; }
  return r;
}
__device__ __forceinline__ f32x4 mfma16(bfrag8 a, bfrag8 b, f32x4 c){
  return __builtin_amdgcn_mfma_f32_16x16x32_bf16(a, b, c, 0, 0, 0);
}

// ---------- dtype-dispatched accessors (flag: 1 = tensor is f32) ----------
__device__ __forceinline__ float ldf(const void* p, size_t i, int f32){
  return f32 ? ((const float*)p)[i] : bf2f(((const unsigned short*)p)[i]);
}
__device__ __forceinline__ unsigned short ldbf(const void* p, size_t i, int f32){
  return f32 ? f2bf(((const float*)p)[i]) : ((const unsigned short*)p)[i];
}
__device__ __forceinline__ bfrag8 load8bf(const void* p, size_t base, int f32){
  if (f32){
    const float* f = (const float*)p + base;
    float4 x = *(const float4*)f;
    float4 y = *(const float4*)(f + 4);
    bfrag8 r;
    r[0]=(short)f2bf(x.x); r[1]=(short)f2bf(x.y); r[2]=(short)f2bf(x.z); r[3]=(short)f2bf(x.w);
    r[4]=(short)f2bf(y.x); r[5]=(short)f2bf(y.y); r[6]=(short)f2bf(y.z); r[7]=(short)f2bf(y.w);
    return r;
  }
  return gload8((const unsigned short*)p + base);
}

// ---------- reductions ----------
template<int CTRL>
__device__ __forceinline__ float dpp_add(float x){
  int xi = __builtin_bit_cast(int, x);
  int yi = __builtin_amdgcn_update_dpp(0, xi, CTRL, 0xF, 0xF, true);
  return x + __builtin_bit_cast(float, yi);
}
__device__ __forceinline__ float row16_sum(float x){
  x = dpp_add<0xB1>(x);    // quad_perm [1,0,3,2]  : + lane^1
  x = dpp_add<0x4E>(x);    // quad_perm [2,3,0,1]  : + lane^2
  x = dpp_add<0x141>(x);   // row_half_mirror      : + other quad
  x = dpp_add<0x140>(x);   // row_mirror           : + other 8-group
  return x;
}
__device__ __forceinline__ float xgrp_sum(float x){
  x += __shfl_xor(x, 16, 64);
  x += __shfl_xor(x, 32, 64);
  return x;
}
__device__ __forceinline__ float xgrp_max(float x){
  x = fmaxf(x, __shfl_xor(x, 16, 64));
  x = fmaxf(x, __shfl_xor(x, 32, 64));
  return x;
}
__device__ __forceinline__ int wave_isum(int x){
#pragma unroll
  for (int s = 1; s < 64; s <<= 1) x += __shfl_xor(x, s, 64);
  return x;
}

// ============================================================================
// Kernel 0a: dtype sniffing — parallel. One wave per tensor; each lane samples
// up to 2 of the first 128 bf16 words; counters shfl-reduced across the wave.
// (Round-5 lesson: the serial 128-load-per-lane version cost ~60 µs alone.)
// ============================================================================
struct Ptrs { const void* p[21]; int n[21]; };
struct PrepPtrs { const void* w[6]; const void* wp; const void* b[11]; };

__global__ void detect_kernel(Ptrs ptrs, int* flags){
  const int lane = threadIdx.x & 63;
  const int wid = blockIdx.x * 4 + (threadIdx.x >> 6);
  if (wid >= 21) return;
  if (wid == 2){ if (lane == 0) flags[2] = 0; return; }   // neighbor_idx is int32

  const unsigned short* p = (const unsigned short*)ptrs.p[wid];
  int m = ptrs.n[wid]; if (m > 128) m = 128;
  int insane = 0, evenZero = 0, evenCnt = 0, oddNZ = 0, oddCnt = 0;
#pragma unroll
  for (int s = 0; s < 2; s++){
    int i = lane + s*64;
    if (i < m){
      unsigned short h = p[i];
      int e = (h >> 7) & 0xFF;
      bool z = (h & 0x7FFF) == 0;
      if (!z && (e == 0xFF || e < 90 || e > 140)) insane++;
      if (i & 1){ oddCnt++;  if (!z) oddNZ++; }
      else      { evenCnt++; if (z)  evenZero++; }
    }
  }
  insane = wave_isum(insane);
  evenZero = wave_isum(evenZero); evenCnt = wave_isum(evenCnt);
  oddNZ = wave_isum(oddNZ);       oddCnt = wave_isum(oddCnt);
  if (lane == 0){
    int f = 0;
    if (insane > 0) f = 1;
    else if (evenZero * 4 >= evenCnt * 3 && oddNZ * 4 >= oddCnt * 3) f = 1;
    flags[wid] = f;
  }
}

// ============================================================================
// Kernel 0b: canonicalize params (parallel, 32 blocks).
// Weights -> fragment-ordered bf16; biases/scales -> f32.
// ============================================================================
__global__ void prep_kernel(PrepPtrs pp, const int* __restrict__ flags,
                            unsigned short* __restrict__ wfrag,
                            unsigned short* __restrict__ wp_bf,
                            float* __restrict__ biases)
{
  const int gid = blockIdx.x * 256 + threadIdx.x;
  const int gstride = gridDim.x * 256;
  const int wflag[6] = {3,5,7,13,17,19};          // wq,wk,wv,wg1,wg2,wo
  for (int idx = gid; idx < 6*4096; idx += gstride){
    int m = idx >> 12;
    int r = idx & 4095;          // ((ks*4+t)*64 + lane)*8 + j
    int j = r & 7;
    int lane = (r >> 3) & 63;
    int kt = r >> 9;
    int ks = kt >> 2, t = kt & 3;
    int o = lane >> 4, rl = lane & 15;
    int src = (ks*32 + o*8 + j)*64 + t*16 + rl;   // B[k][n] fragment element
    wfrag[idx] = ldbf(pp.w[m], src, flags[wflag[m]]);
  }
  if (blockIdx.x == 0){
    for (int i = threadIdx.x; i < 192; i += 256) wp_bf[i] = ldbf(pp.wp, i, flags[9]);
    const int bflag[11] = {4,6,8,10,11,12,14,15,16,18,20};
    for (int i = threadIdx.x; i < 11*64; i += 256){
      int m = i >> 6;
      biases[i] = ldf(pp.b[m], i & 63, flags[bflag[m]]);
    }
  }
}

// ============================================================================
// Kernel 1: q,k,v = features @ {wq,wk,wv} + bias -> bf16 scratch.
// ============================================================================
__global__ __launch_bounds__(256, 2)
void qkv_kernel(const void* __restrict__ feat,
                const unsigned short* __restrict__ wfrag,
                const float* __restrict__ biases,
                unsigned short* __restrict__ q_ws, unsigned short* __restrict__ k_ws,
                unsigned short* __restrict__ v_ws, const int* __restrict__ flags, int N)
{
  const int F_feat = flags[1];
  const int lane = threadIdx.x & 63;
  const int wave = threadIdx.x >> 6;
  const int o = lane >> 4, rl = lane & 15;

  bfrag8 wqf[2][4], wkf[2][4], wvf[2][4];
#pragma unroll
  for (int ks = 0; ks < 2; ks++)
#pragma unroll
    for (int t = 0; t < 4; t++){
      int off = ((ks*4 + t)*64 + lane)*8;
      wqf[ks][t] = gload8(wfrag + off);
      wkf[ks][t] = gload8(wfrag + 4096 + off);
      wvf[ks][t] = gload8(wfrag + 8192 + off);
    }
  float bqC[4], bkC[4], bvC[4];
#pragma unroll
  for (int t = 0; t < 4; t++){
    bqC[t] = biases[0*64 + t*16 + rl];
    bkC[t] = biases[1*64 + t*16 + rl];
    bvC[t] = biases[2*64 + t*16 + rl];
  }

  const int ntiles = (N + 15) >> 4;
  for (int tile = blockIdx.x*4 + wave; tile < ntiles; tile += gridDim.x*4){
    const int n0 = tile * 16;
    int ar = n0 + rl; if (ar >= N) ar = N - 1;
    bfrag8 a[2];
#pragma unroll
    for (int ks = 0; ks < 2; ks++) a[ks] = load8bf(feat, (size_t)ar*64 + ks*32 + o*8, F_feat);

#pragma unroll
    for (int t = 0; t < 4; t++){
      f32x4 zq = {0.f,0.f,0.f,0.f}, zk = {0.f,0.f,0.f,0.f}, zv = {0.f,0.f,0.f,0.f};
#pragma unroll
      for (int ks = 0; ks < 2; ks++){
        zq = mfma16(a[ks], wqf[ks][t], zq);
        zk = mfma16(a[ks], wkf[ks][t], zk);
        zv = mfma16(a[ks], wvf[ks][t], zv);
      }
#pragma unroll
      for (int q = 0; q < 4; q++){
        size_t row = n0 + o*4 + q; int col = t*16 + rl;
        if ((int)row < N){
          q_ws[row*64 + col] = f2bf(zq[q] + bqC[t]);
          k_ws[row*64 + col] = f2bf(zk[q] + bkC[t]);
          v_ws[row*64 + col] = f2bf(zv[q] + bvC[t]);
        }
      }
    }
  }
}

// ============================================================================
// Kernel 2: fused point-transformer. 256-thread blocks, one wave per point.
// q/gk/gv gathered directly in C-layout; attn_in formed in C-layout registers
// (GEMM1 is 8 MFMAs, chain depth 2 — round-5's 3-chain version was 24).
// NOTE: weight fragments live in VGPRs (~96) — do NOT tighten launch bounds:
// round-4's (64,4) clamped VGPR to 64 and spilled ~1 GB/launch.
// ============================================================================
__global__ __launch_bounds__(256, 2)
void pt_kernel(const void* __restrict__ points,
               const void* __restrict__ feat,
               const int* __restrict__ nidx,
               const unsigned short* __restrict__ q_ws,
               const unsigned short* __restrict__ k_ws,
               const unsigned short* __restrict__ v_ws,
               const unsigned short* __restrict__ wfrag,
               const unsigned short* __restrict__ wp_bf,
               const float* __restrict__ biases,
               const int* __restrict__ flags, void* __restrict__ out, int N)
{
  __shared__ unsigned short xbuf[4][16][68];   // per-wave C<->A bounce (stride 68)
  __shared__ unsigned short ybuf[4][64];

  const int F_pts = flags[0], F_feat = flags[1];
  const int lane = threadIdx.x & 63;
  const int wave = threadIdx.x >> 6;
  const int o = lane >> 4, rl = lane & 15;

  // ---- per-wave constants ----
  bfrag8 wg1f[2][4], wg2f[2][4], wof[2][4];
#pragma unroll
  for (int ks = 0; ks < 2; ks++)
#pragma unroll
    for (int t = 0; t < 4; t++){
      int off = ((ks*4 + t)*64 + lane)*8;
      wg1f[ks][t] = gload8(wfrag + 3*4096 + off);
      wg2f[ks][t] = gload8(wfrag + 4*4096 + off);
      wof[ks][t]  = gload8(wfrag + 5*4096 + off);
    }
  bfrag8 wpf[4];
#pragma unroll
  for (int t = 0; t < 4; t++){
    bfrag8 a = {0,0,0,0,0,0,0,0};
    if (o == 0){
#pragma unroll
      for (int j = 0; j < 3; j++) a[j] = (short)wp_bf[j*64 + t*16 + rl];
    }
    wpf[t] = a;
  }
  float bpC[4], gpC[4], bePC[4], bg1C[4], ggC[4], beGC[4], bg2C[4], boC[4];
#pragma unroll
  for (int t = 0; t < 4; t++){
    int c = t*16 + rl;
    bpC[t]  = biases[3*64 + c];  gpC[t]  = biases[4*64 + c];  bePC[t] = biases[5*64 + c];
    bg1C[t] = biases[6*64 + c];  ggC[t]  = biases[7*64 + c];  beGC[t] = biases[8*64 + c];
    bg2C[t] = biases[9*64 + c];  boC[t]  = biases[10*64 + c];
  }

  const int wstride = gridDim.x * 4;
  for (int n = blockIdx.x*4 + wave; n < N; n += wstride){
    const int jr = nidx[n*16 + rl];          // neighbor for A-layout row rl (p path)
    int jq[4];
#pragma unroll
    for (int q = 0; q < 4; q++) jq[q] = nidx[n*16 + o*4 + q];   // C-layout rows

    // ---- C-layout gathers: q (broadcast), gk, gv ----
    float qC[4], gkC[4][4], gvC[4][4];
#pragma unroll
    for (int t = 0; t < 4; t++) qC[t] = bf2f(q_ws[(size_t)n*64 + t*16 + rl]);
#pragma unroll
    for (int q = 0; q < 4; q++)
#pragma unroll
      for (int t = 0; t < 4; t++){
        gkC[t][q] = bf2f(k_ws[(size_t)jq[q]*64 + t*16 + rl]);
        gvC[t][q] = bf2f(v_ws[(size_t)jq[q]*64 + t*16 + rl]);
      }
    const float res = ldf(feat, (size_t)n*64 + lane, F_feat);
    float rel[3];
#pragma unroll
    for (int d = 0; d < 3; d++)
      rel[d] = ldf(points, (size_t)jr*3 + d, F_pts) - ldf(points, (size_t)n*3 + d, F_pts);

    // ---- p = relu(LN(rel @ wp + bp)) via MFMA (K padded 3->32) ----
    bfrag8 ap = {0,0,0,0,0,0,0,0};
    if (o == 0){
#pragma unroll
      for (int d = 0; d < 3; d++) ap[d] = (short)f2bf(rel[d]);
    }
    f32x4 pacc[4];
#pragma unroll
    for (int t = 0; t < 4; t++){
      f32x4 z = {0.f,0.f,0.f,0.f};
      pacc[t] = mfma16(ap, wpf[t], z);
    }
    float p_val[4][4];                        // [t][q], C-layout
#pragma unroll
    for (int q = 0; q < 4; q++){
      float xv[4]; float s = 0.f, s2 = 0.f;
#pragma unroll
      for (int t = 0; t < 4; t++){ xv[t] = pacc[t][q] + bpC[t]; s += xv[t]; s2 += xv[t]*xv[t]; }
      s = row16_sum(s); s2 = row16_sum(s2);
      float mu = s * (1.f/64.f);
      float var = s2 * (1.f/64.f) - mu*mu;
      float rs = rsqrtf(var + 1e-5f);
#pragma unroll
      for (int t = 0; t < 4; t++){
        float v = (xv[t] - mu) * rs * gpC[t] + bePC[t];
        p_val[t][q] = fmaxf(v, 0.f);
      }
    }

    // ---- attn_in = q - gk + p in C-layout; bounce C->A; GEMM1 (8 MFMAs) ----
#pragma unroll
    for (int q = 0; q < 4; q++)
#pragma unroll
      for (int t = 0; t < 4; t++)
        xbuf[wave][o*4 + q][t*16 + rl] = f2bf(qC[t] - gkC[t][q] + p_val[t][q]);
    f32x4 hacc[4] = {{0.f,0.f,0.f,0.f},{0.f,0.f,0.f,0.f},{0.f,0.f,0.f,0.f},{0.f,0.f,0.f,0.f}};
#pragma unroll
    for (int ks = 0; ks < 2; ks++){
      bfrag8 af = lds_load8(&xbuf[wave][rl][ks*32 + o*8]);
#pragma unroll
      for (int t = 0; t < 4; t++) hacc[t] = mfma16(af, wg1f[ks][t], hacc[t]);
    }

    // ---- LN + relu -> h ----
    float h_val[4][4];
#pragma unroll
    for (int q = 0; q < 4; q++){
      float xv[4]; float s = 0.f, s2 = 0.f;
#pragma unroll
      for (int t = 0; t < 4; t++){ xv[t] = hacc[t][q] + bg1C[t]; s += xv[t]; s2 += xv[t]*xv[t]; }
      s = row16_sum(s); s2 = row16_sum(s2);
      float mu = s * (1.f/64.f);
      float var = s2 * (1.f/64.f) - mu*mu;
      float rs = rsqrtf(var + 1e-5f);
#pragma unroll
      for (int t = 0; t < 4; t++){
        float v = (xv[t] - mu) * rs * ggC[t] + beGC[t];
        h_val[t][q] = fmaxf(v, 0.f);
      }
    }

    // ---- h: C->A; GEMM2 ----
#pragma unroll
    for (int q = 0; q < 4; q++)
#pragma unroll
      for (int t = 0; t < 4; t++) xbuf[wave][o*4 + q][t*16 + rl] = f2bf(h_val[t][q]);
    f32x4 wacc[4] = {{0.f,0.f,0.f,0.f},{0.f,0.f,0.f,0.f},{0.f,0.f,0.f,0.f},{0.f,0.f,0.f,0.f}};
#pragma unroll
    for (int ks = 0; ks < 2; ks++){
      bfrag8 hf = lds_load8(&xbuf[wave][rl][ks*32 + o*8]);
#pragma unroll
      for (int t = 0; t < 4; t++) wacc[t] = mfma16(hf, wg2f[ks][t], wacc[t]);
    }

    // ---- softmax over neighbors + weighted sum ----
    float y[4];
#pragma unroll
    for (int t = 0; t < 4; t++){
      float wv[4];
#pragma unroll
      for (int q = 0; q < 4; q++) wv[q] = wacc[t][q] + bg2C[t];
      float mx = fmaxf(fmaxf(wv[0], wv[1]), fmaxf(wv[2], wv[3]));
      mx = xgrp_max(mx);
      float se = 0.f, z = 0.f;
#pragma unroll
      for (int q = 0; q < 4; q++){
        float e = __expf(wv[q] - mx);
        se += e;
        z  += e * (gvC[t][q] + p_val[t][q]);
      }
      se = xgrp_sum(se); z = xgrp_sum(z);
      y[t] = z / se;
    }

    // ---- out = y @ wo + bo + residual ----
    if (o == 0){
#pragma unroll
      for (int t = 0; t < 4; t++) ybuf[wave][t*16 + rl] = f2bf(y[t]);
    }
    f32x4 oacc[4] = {{0.f,0.f,0.f,0.f},{0.f,0.f,0.f,0.f},{0.f,0.f,0.f,0.f},{0.f,0.f,0.f,0.f}};
#pragma unroll
    for (int ks = 0; ks < 2; ks++){
      bfrag8 yf = lds_load8(&ybuf[wave][ks*32 + o*8]);
#pragma unroll
      for (int t = 0; t < 4; t++) oacc[t] = mfma16(yf, wof[ks][t], oacc[t]);
    }

    float ov = 0.f;
#pragma unroll
    for (int t = 0; t < 4; t++) if (o == t) ov = oacc[t][0] + boC[t];
    float outv = ov + res;
    if (F_feat) ((float*)out)[(size_t)n*64 + lane] = outv;
    else ((unsigned short*)out)[(size_t)n*64 + lane] = f2bf(outv);
  }
}

// ============================================================================
extern "C" void kernel_launch(void* const* d_in, const int* in_sizes, int n_in,
                              void* d_out, int out_size, void* d_ws, size_t ws_size,
                              hipStream_t stream)
{
  const int N = in_sizes[1] / 64;

  unsigned short* q_ws = (unsigned short*)d_ws;
  unsigned short* k_ws = q_ws + (size_t)N * 64;
  unsigned short* v_ws = k_ws + (size_t)N * 64;
  char* base = (char*)d_ws + (size_t)3 * N * 64 * sizeof(unsigned short);
  int*            flags  = (int*)base;                            // 128 B
  unsigned short* wfrag  = (unsigned short*)(base + 256);         // 49152 B
  unsigned short* wp_bf  = (unsigned short*)(base + 256 + 49152); // 384 B (pad 512)
  float*          biases = (float*)(base + 256 + 49152 + 512);    // 2816 B

  Ptrs ptrs;
  for (int i = 0; i < 21; i++){ ptrs.p[i] = d_in[i]; ptrs.n[i] = in_sizes[i]; }
  PrepPtrs pp;
  pp.w[0] = d_in[3];  pp.w[1] = d_in[5];  pp.w[2] = d_in[7];
  pp.w[3] = d_in[13]; pp.w[4] = d_in[17]; pp.w[5] = d_in[19];
  pp.wp = d_in[9];
  pp.b[0] = d_in[4];  pp.b[1] = d_in[6];  pp.b[2] = d_in[8];  pp.b[3] = d_in[10];
  pp.b[4] = d_in[11]; pp.b[5] = d_in[12]; pp.b[6] = d_in[14]; pp.b[7] = d_in[15];
  pp.b[8] = d_in[16]; pp.b[9] = d_in[18]; pp.b[10] = d_in[20];

  detect_kernel<<<6, 256, 0, stream>>>(ptrs, flags);
  prep_kernel<<<32, 256, 0, stream>>>(pp, flags, wfrag, wp_bf, biases);
  qkv_kernel<<<512, 256, 0, stream>>>(d_in[1], wfrag, biases, q_ws, k_ws, v_ws, flags, N);
  pt_kernel<<<1024, 256, 0, stream>>>(d_in[0], d_in[1], (const int*)d_in[2], q_ws, k_ws, v_ws,
                                      wfrag, wp_bf, biases, flags, d_out, N);
}

// Round 7
// 214.728 us; speedup vs baseline: 2.0065x; 1.0476x over previous
//
#include <hip/hip_runtime.h>

// ---------- types ----------
typedef __attribute__((ext_vector_type(8))) short bfrag8;   // 8 bf16 bit patterns (4 VGPRs)
typedef __attribute__((ext_vector_type(4))) short bfrag4;
typedef __attribute__((ext_vector_type(4))) float f32x4;

#if defined(__has_builtin)
#if __has_builtin(__builtin_amdgcn_cvt_pk_bf16_f32)
#define HAVE_PK_BF16 1
#endif
#endif

// ---------- bf16 helpers ----------
__device__ __forceinline__ float bf2f(unsigned short h){
  unsigned u = ((unsigned)h) << 16;
  return __builtin_bit_cast(float, u);
}
__device__ __forceinline__ unsigned short f2bf(float f){
  unsigned u = __builtin_bit_cast(unsigned, f);
  u = u + 0x7FFFu + ((u >> 16) & 1u);        // round-to-nearest-even
  return (unsigned short)(u >> 16);
}
// pack two f32 -> two bf16 in one dword (lo=a, hi=b); single instr on gfx950
__device__ __forceinline__ unsigned pk2bf(float a, float b){
#ifdef HAVE_PK_BF16
  typedef __attribute__((ext_vector_type(2))) __bf16 bf16x2_t;
  bf16x2_t r = __builtin_amdgcn_cvt_pk_bf16_f32(a, b);
  return __builtin_bit_cast(unsigned, r);
#else
  return (unsigned)f2bf(a) | ((unsigned)f2bf(b) << 16);
#endif
}
__device__ __forceinline__ bfrag8 gload8(const unsigned short* p){ // 16B-aligned global, bf16
  int4 v = *(const int4*)p;
  return __builtin_bit_cast(bfrag8, v);
}
__device__ __forceinline__ bfrag8 lds_load8(const unsigned short* p){ // 8B-aligned LDS
  bfrag4 lo = *(const bfrag4*)p;
  bfrag4 hi = *(const bfrag4*)(p + 4);
  bfrag8 r;
#pragma unroll
  for (int j = 0; j < 4; j++){ r[j] = lo[j]; r[4+j] = hi[j]; }
  return r;
}
__device__ __forceinline__ f32x4 mfma16(bfrag8 a, bfrag8 b, f32x4 c){
  return __builtin_amdgcn_mfma_f32_16x16x32_bf16(a, b, c, 0, 0, 0);
}

// ---------- dtype-dispatched accessors (flag: 1 = tensor is f32) ----------
__device__ __forceinline__ float ldf(const void* p, size_t i, int f32){
  return f32 ? ((const float*)p)[i] : bf2f(((const unsigned short*)p)[i]);
}
__device__ __forceinline__ unsigned short ldbf(const void* p, size_t i, int f32){
  return f32 ? f2bf(((const float*)p)[i]) : ((const unsigned short*)p)[i];
}
__device__ __forceinline__ bfrag8 load8bf(const void* p, size_t base, int f32){
  if (f32){
    const float* f = (const float*)p + base;
    float4 x = *(const float4*)f;
    float4 y = *(const float4*)(f + 4);
    bfrag8 r;
    r[0]=(short)f2bf(x.x); r[1]=(short)f2bf(x.y); r[2]=(short)f2bf(x.z); r[3]=(short)f2bf(x.w);
    r[4]=(short)f2bf(y.x); r[5]=(short)f2bf(y.y); r[6]=(short)f2bf(y.z); r[7]=(short)f2bf(y.w);
    return r;
  }
  return gload8((const unsigned short*)p + base);
}

// ---------- reductions ----------
template<int CTRL>
__device__ __forceinline__ float dpp_add(float x){
  int xi = __builtin_bit_cast(int, x);
  int yi = __builtin_amdgcn_update_dpp(0, xi, CTRL, 0xF, 0xF, true);
  return x + __builtin_bit_cast(float, yi);
}
__device__ __forceinline__ float row16_sum(float x){
  x = dpp_add<0xB1>(x);    // quad_perm [1,0,3,2]  : + lane^1
  x = dpp_add<0x4E>(x);    // quad_perm [2,3,0,1]  : + lane^2
  x = dpp_add<0x141>(x);   // row_half_mirror      : + other quad
  x = dpp_add<0x140>(x);   // row_mirror           : + other 8-group
  return x;
}
__device__ __forceinline__ float xgrp_sum(float x){
  x += __shfl_xor(x, 16, 64);
  x += __shfl_xor(x, 32, 64);
  return x;
}
__device__ __forceinline__ int wave_isum(int x){
#pragma unroll
  for (int s = 1; s < 64; s <<= 1) x += __shfl_xor(x, s, 64);
  return x;
}

// ============================================================================
// Kernel 0a: dtype sniffing — parallel, one wave per tensor.
// ============================================================================
struct Ptrs { const void* p[21]; int n[21]; };
struct PrepPtrs { const void* w[6]; const void* wp; const void* b[11]; };

__global__ void detect_kernel(Ptrs ptrs, int* flags){
  const int lane = threadIdx.x & 63;
  const int wid = blockIdx.x * 4 + (threadIdx.x >> 6);
  if (wid >= 21) return;
  if (wid == 2){ if (lane == 0) flags[2] = 0; return; }   // neighbor_idx is int32

  const unsigned short* p = (const unsigned short*)ptrs.p[wid];
  int m = ptrs.n[wid]; if (m > 128) m = 128;
  int insane = 0, evenZero = 0, evenCnt = 0, oddNZ = 0, oddCnt = 0;
#pragma unroll
  for (int s = 0; s < 2; s++){
    int i = lane + s*64;
    if (i < m){
      unsigned short h = p[i];
      int e = (h >> 7) & 0xFF;
      bool z = (h & 0x7FFF) == 0;
      if (!z && (e == 0xFF || e < 90 || e > 140)) insane++;
      if (i & 1){ oddCnt++;  if (!z) oddNZ++; }
      else      { evenCnt++; if (z)  evenZero++; }
    }
  }
  insane = wave_isum(insane);
  evenZero = wave_isum(evenZero); evenCnt = wave_isum(evenCnt);
  oddNZ = wave_isum(oddNZ);       oddCnt = wave_isum(oddCnt);
  if (lane == 0){
    int f = 0;
    if (insane > 0) f = 1;
    else if (evenZero * 4 >= evenCnt * 3 && oddNZ * 4 >= oddCnt * 3) f = 1;
    flags[wid] = f;
  }
}

// ============================================================================
// Kernel 0b: canonicalize params. Weights -> fragment-ordered bf16.
// ============================================================================
__global__ void prep_kernel(PrepPtrs pp, const int* __restrict__ flags,
                            unsigned short* __restrict__ wfrag,
                            unsigned short* __restrict__ wp_bf,
                            float* __restrict__ biases)
{
  const int gid = blockIdx.x * 256 + threadIdx.x;
  const int gstride = gridDim.x * 256;
  const int wflag[6] = {3,5,7,13,17,19};          // wq,wk,wv,wg1,wg2,wo
  for (int idx = gid; idx < 6*4096; idx += gstride){
    int m = idx >> 12;
    int r = idx & 4095;          // ((ks*4+t)*64 + lane)*8 + j
    int j = r & 7;
    int lane = (r >> 3) & 63;
    int kt = r >> 9;
    int ks = kt >> 2, t = kt & 3;
    int o = lane >> 4, rl = lane & 15;
    int src = (ks*32 + o*8 + j)*64 + t*16 + rl;   // B[k][n] fragment element
    wfrag[idx] = ldbf(pp.w[m], src, flags[wflag[m]]);
  }
  if (blockIdx.x == 0){
    for (int i = threadIdx.x; i < 192; i += 256) wp_bf[i] = ldbf(pp.wp, i, flags[9]);
    const int bflag[11] = {4,6,8,10,11,12,14,15,16,18,20};
    for (int i = threadIdx.x; i < 11*64; i += 256){
      int m = i >> 6;
      biases[i] = ldf(pp.b[m], i & 63, flags[bflag[m]]);
    }
  }
}

// ============================================================================
// Kernel 1: q,k,v = features @ {wq,wk,wv} + bias -> bf16 scratch in SWIZZLED
// layout: element (row, c) stored at row*64 + 4*(c&15) + (c>>4), so one lane's
// four channels {rl, rl+16, rl+32, rl+48} are 8B-contiguous (dwordx2 I/O).
// ============================================================================
__global__ __launch_bounds__(256, 2)
void qkv_kernel(const void* __restrict__ feat,
                const unsigned short* __restrict__ wfrag,
                const float* __restrict__ biases,
                unsigned short* __restrict__ q_ws, unsigned short* __restrict__ k_ws,
                unsigned short* __restrict__ v_ws, const int* __restrict__ flags, int N)
{
  const int F_feat = flags[1];
  const int lane = threadIdx.x & 63;
  const int wave = threadIdx.x >> 6;
  const int o = lane >> 4, rl = lane & 15;

  bfrag8 wqf[2][4], wkf[2][4], wvf[2][4];
#pragma unroll
  for (int ks = 0; ks < 2; ks++)
#pragma unroll
    for (int t = 0; t < 4; t++){
      int off = ((ks*4 + t)*64 + lane)*8;
      wqf[ks][t] = gload8(wfrag + off);
      wkf[ks][t] = gload8(wfrag + 4096 + off);
      wvf[ks][t] = gload8(wfrag + 8192 + off);
    }
  float bqC[4], bkC[4], bvC[4];
#pragma unroll
  for (int t = 0; t < 4; t++){
    bqC[t] = biases[0*64 + t*16 + rl];
    bkC[t] = biases[1*64 + t*16 + rl];
    bvC[t] = biases[2*64 + t*16 + rl];
  }

  const int ntiles = (N + 15) >> 4;
  for (int tile = blockIdx.x*4 + wave; tile < ntiles; tile += gridDim.x*4){
    const int n0 = tile * 16;
    int ar = n0 + rl; if (ar >= N) ar = N - 1;
    bfrag8 a[2];
#pragma unroll
    for (int ks = 0; ks < 2; ks++) a[ks] = load8bf(feat, (size_t)ar*64 + ks*32 + o*8, F_feat);

    f32x4 zq[4], zk[4], zv[4];
#pragma unroll
    for (int t = 0; t < 4; t++){
      f32x4 aq = {0.f,0.f,0.f,0.f}, ak = {0.f,0.f,0.f,0.f}, av = {0.f,0.f,0.f,0.f};
#pragma unroll
      for (int ks = 0; ks < 2; ks++){
        aq = mfma16(a[ks], wqf[ks][t], aq);
        ak = mfma16(a[ks], wkf[ks][t], ak);
        av = mfma16(a[ks], wvf[ks][t], av);
      }
      zq[t] = aq; zk[t] = ak; zv[t] = av;
    }
#pragma unroll
    for (int q = 0; q < 4; q++){
      size_t row = n0 + o*4 + q;
      if ((int)row < N){
        size_t e = row*64 + 4*rl;
        uint2 u;
        u.x = pk2bf(zq[0][q]+bqC[0], zq[1][q]+bqC[1]);
        u.y = pk2bf(zq[2][q]+bqC[2], zq[3][q]+bqC[3]);
        *(uint2*)(q_ws + e) = u;
        u.x = pk2bf(zk[0][q]+bkC[0], zk[1][q]+bkC[1]);
        u.y = pk2bf(zk[2][q]+bkC[2], zk[3][q]+bkC[3]);
        *(uint2*)(k_ws + e) = u;
        u.x = pk2bf(zv[0][q]+bvC[0], zv[1][q]+bvC[1]);
        u.y = pk2bf(zv[2][q]+bvC[2], zv[3][q]+bvC[3]);
        *(uint2*)(v_ws + e) = u;
      }
    }
  }
}

// ============================================================================
// Kernel 2: fused point-transformer. 256-thread blocks, one wave per point.
// q/gk/gv gathered as dwordx2 from the swizzled scratch (C-layout direct).
// NOTE: weight fragments live in VGPRs (~96) — do NOT tighten launch bounds:
// round-4's (64,4) clamped VGPR to 64 and spilled ~1 GB/launch.
// ============================================================================
__global__ __launch_bounds__(256, 2)
void pt_kernel(const void* __restrict__ points,
               const void* __restrict__ feat,
               const int* __restrict__ nidx,
               const unsigned short* __restrict__ q_ws,
               const unsigned short* __restrict__ k_ws,
               const unsigned short* __restrict__ v_ws,
               const unsigned short* __restrict__ wfrag,
               const unsigned short* __restrict__ wp_bf,
               const float* __restrict__ biases,
               const int* __restrict__ flags, void* __restrict__ out, int N)
{
  __shared__ unsigned short xbuf[4][16][68];   // per-wave C<->A bounce (stride 68)
  __shared__ unsigned short ybuf[4][64];

  const int F_pts = flags[0], F_feat = flags[1];
  const int lane = threadIdx.x & 63;
  const int wave = threadIdx.x >> 6;
  const int o = lane >> 4, rl = lane & 15;

  // ---- per-wave constants ----
  bfrag8 wg1f[2][4], wg2f[2][4], wof[2][4];
#pragma unroll
  for (int ks = 0; ks < 2; ks++)
#pragma unroll
    for (int t = 0; t < 4; t++){
      int off = ((ks*4 + t)*64 + lane)*8;
      wg1f[ks][t] = gload8(wfrag + 3*4096 + off);
      wg2f[ks][t] = gload8(wfrag + 4*4096 + off);
      wof[ks][t]  = gload8(wfrag + 5*4096 + off);
    }
  bfrag8 wpf[4];
#pragma unroll
  for (int t = 0; t < 4; t++){
    bfrag8 a = {0,0,0,0,0,0,0,0};
    if (o == 0){
#pragma unroll
      for (int j = 0; j < 3; j++) a[j] = (short)wp_bf[j*64 + t*16 + rl];
    }
    wpf[t] = a;
  }
  float bpC[4], gpC[4], bePC[4], bg1C[4], ggC[4], beGC[4], bg2C[4], boC[4];
#pragma unroll
  for (int t = 0; t < 4; t++){
    int c = t*16 + rl;
    bpC[t]  = biases[3*64 + c];  gpC[t]  = biases[4*64 + c];  bePC[t] = biases[5*64 + c];
    bg1C[t] = biases[6*64 + c];  ggC[t]  = biases[7*64 + c];  beGC[t] = biases[8*64 + c];
    bg2C[t] = biases[9*64 + c];  boC[t]  = biases[10*64 + c];
  }

  const int wstride = gridDim.x * 4;
  for (int n = blockIdx.x*4 + wave; n < N; n += wstride){
    const int jr = nidx[n*16 + rl];          // neighbor for A-layout row rl (p path)
    int jq[4];
#pragma unroll
    for (int q = 0; q < 4; q++) jq[q] = nidx[n*16 + o*4 + q];   // C-layout rows

    // ---- C-layout gathers via swizzled dwordx2: q (broadcast), gk, gv ----
    float qC[4], gkC[4][4], gvC[4][4];
    {
      ushort4 uq = *(const ushort4*)(q_ws + (size_t)n*64 + 4*rl);
      qC[0] = bf2f(uq.x); qC[1] = bf2f(uq.y); qC[2] = bf2f(uq.z); qC[3] = bf2f(uq.w);
    }
#pragma unroll
    for (int q = 0; q < 4; q++){
      size_t e = (size_t)jq[q]*64 + 4*rl;
      ushort4 uk = *(const ushort4*)(k_ws + e);
      ushort4 uv = *(const ushort4*)(v_ws + e);
      gkC[0][q] = bf2f(uk.x); gkC[1][q] = bf2f(uk.y); gkC[2][q] = bf2f(uk.z); gkC[3][q] = bf2f(uk.w);
      gvC[0][q] = bf2f(uv.x); gvC[1][q] = bf2f(uv.y); gvC[2][q] = bf2f(uv.z); gvC[3][q] = bf2f(uv.w);
    }
    const float res = ldf(feat, (size_t)n*64 + lane, F_feat);
    float rel[3];
#pragma unroll
    for (int d = 0; d < 3; d++)
      rel[d] = ldf(points, (size_t)jr*3 + d, F_pts) - ldf(points, (size_t)n*3 + d, F_pts);

    // ---- p = relu(LN(rel @ wp + bp)) via MFMA (K padded 3->32) ----
    bfrag8 ap = {0,0,0,0,0,0,0,0};
    if (o == 0){
#pragma unroll
      for (int d = 0; d < 3; d++) ap[d] = (short)f2bf(rel[d]);
    }
    f32x4 pacc[4];
#pragma unroll
    for (int t = 0; t < 4; t++){
      f32x4 z = {0.f,0.f,0.f,0.f};
      pacc[t] = mfma16(ap, wpf[t], z);
    }
    float p_val[4][4];                        // [t][q], C-layout
#pragma unroll
    for (int q = 0; q < 4; q++){
      float xv[4]; float s = 0.f, s2 = 0.f;
#pragma unroll
      for (int t = 0; t < 4; t++){ xv[t] = pacc[t][q] + bpC[t]; s += xv[t]; s2 += xv[t]*xv[t]; }
      s = row16_sum(s); s2 = row16_sum(s2);
      float mu = s * (1.f/64.f);
      float var = s2 * (1.f/64.f) - mu*mu;
      float rs = rsqrtf(var + 1e-5f);
#pragma unroll
      for (int t = 0; t < 4; t++){
        float a = rs * gpC[t];
        p_val[t][q] = fmaxf(xv[t]*a + (bePC[t] - mu*a), 0.f);
      }
    }

    // ---- attn_in = q - gk + p in C-layout; bounce C->A (paired bf16 pack) ----
#pragma unroll
    for (int q = 0; q < 4; q++){
      float a0 = qC[0] - gkC[0][q] + p_val[0][q];
      float a1 = qC[1] - gkC[1][q] + p_val[1][q];
      float a2 = qC[2] - gkC[2][q] + p_val[2][q];
      float a3 = qC[3] - gkC[3][q] + p_val[3][q];
      unsigned u01 = pk2bf(a0, a1), u23 = pk2bf(a2, a3);
      int r = o*4 + q;
      xbuf[wave][r][0*16 + rl] = (unsigned short)u01;
      xbuf[wave][r][1*16 + rl] = (unsigned short)(u01 >> 16);
      xbuf[wave][r][2*16 + rl] = (unsigned short)u23;
      xbuf[wave][r][3*16 + rl] = (unsigned short)(u23 >> 16);
    }
    f32x4 hacc[4] = {{0.f,0.f,0.f,0.f},{0.f,0.f,0.f,0.f},{0.f,0.f,0.f,0.f},{0.f,0.f,0.f,0.f}};
#pragma unroll
    for (int ks = 0; ks < 2; ks++){
      bfrag8 af = lds_load8(&xbuf[wave][rl][ks*32 + o*8]);
#pragma unroll
      for (int t = 0; t < 4; t++) hacc[t] = mfma16(af, wg1f[ks][t], hacc[t]);
    }

    // ---- LN + relu -> h; bounce C->A; GEMM2 ----
    float h_val[4][4];
#pragma unroll
    for (int q = 0; q < 4; q++){
      float xv[4]; float s = 0.f, s2 = 0.f;
#pragma unroll
      for (int t = 0; t < 4; t++){ xv[t] = hacc[t][q] + bg1C[t]; s += xv[t]; s2 += xv[t]*xv[t]; }
      s = row16_sum(s); s2 = row16_sum(s2);
      float mu = s * (1.f/64.f);
      float var = s2 * (1.f/64.f) - mu*mu;
      float rs = rsqrtf(var + 1e-5f);
#pragma unroll
      for (int t = 0; t < 4; t++){
        float a = rs * ggC[t];
        h_val[t][q] = fmaxf(xv[t]*a + (beGC[t] - mu*a), 0.f);
      }
      unsigned u01 = pk2bf(h_val[0][q], h_val[1][q]);
      unsigned u23 = pk2bf(h_val[2][q], h_val[3][q]);
      int r = o*4 + q;
      // note: overwrites xbuf AFTER attn A-frags were consumed above
      xbuf[wave][r][0*16 + rl] = (unsigned short)u01;
      xbuf[wave][r][1*16 + rl] = (unsigned short)(u01 >> 16);
      xbuf[wave][r][2*16 + rl] = (unsigned short)u23;
      xbuf[wave][r][3*16 + rl] = (unsigned short)(u23 >> 16);
    }
    f32x4 wacc[4] = {{0.f,0.f,0.f,0.f},{0.f,0.f,0.f,0.f},{0.f,0.f,0.f,0.f},{0.f,0.f,0.f,0.f}};
#pragma unroll
    for (int ks = 0; ks < 2; ks++){
      bfrag8 hf = lds_load8(&xbuf[wave][rl][ks*32 + o*8]);
#pragma unroll
      for (int t = 0; t < 4; t++) wacc[t] = mfma16(hf, wg2f[ks][t], wacc[t]);
    }

    // ---- softmax over neighbors (no max-shift: |w| << 88, f32 exp safe) ----
    float y[4];
#pragma unroll
    for (int t = 0; t < 4; t++){
      float se = 0.f, z = 0.f;
#pragma unroll
      for (int q = 0; q < 4; q++){
        float e = __expf(wacc[t][q] + bg2C[t]);
        se += e;
        z  += e * (gvC[t][q] + p_val[t][q]);
      }
      se = xgrp_sum(se); z = xgrp_sum(z);
      y[t] = z * __builtin_amdgcn_rcpf(se);
    }

    // ---- out = y @ wo + bo + residual ----
    if (o == 0){
      unsigned u01 = pk2bf(y[0], y[1]), u23 = pk2bf(y[2], y[3]);
      ybuf[wave][0*16 + rl] = (unsigned short)u01;
      ybuf[wave][1*16 + rl] = (unsigned short)(u01 >> 16);
      ybuf[wave][2*16 + rl] = (unsigned short)u23;
      ybuf[wave][3*16 + rl] = (unsigned short)(u23 >> 16);
    }
    f32x4 oacc[4] = {{0.f,0.f,0.f,0.f},{0.f,0.f,0.f,0.f},{0.f,0.f,0.f,0.f},{0.f,0.f,0.f,0.f}};
#pragma unroll
    for (int ks = 0; ks < 2; ks++){
      bfrag8 yf = lds_load8(&ybuf[wave][ks*32 + o*8]);
#pragma unroll
      for (int t = 0; t < 4; t++) oacc[t] = mfma16(yf, wof[ks][t], oacc[t]);
    }

    float ov = 0.f;
#pragma unroll
    for (int t = 0; t < 4; t++) if (o == t) ov = oacc[t][0] + boC[t];
    float outv = ov + res;
    if (F_feat) ((float*)out)[(size_t)n*64 + lane] = outv;
    else ((unsigned short*)out)[(size_t)n*64 + lane] = f2bf(outv);
  }
}

// ============================================================================
extern "C" void kernel_launch(void* const* d_in, const int* in_sizes, int n_in,
                              void* d_out, int out_size, void* d_ws, size_t ws_size,
                              hipStream_t stream)
{
  const int N = in_sizes[1] / 64;

  unsigned short* q_ws = (unsigned short*)d_ws;
  unsigned short* k_ws = q_ws + (size_t)N * 64;
  unsigned short* v_ws = k_ws + (size_t)N * 64;
  char* base = (char*)d_ws + (size_t)3 * N * 64 * sizeof(unsigned short);
  int*            flags  = (int*)base;                            // 128 B
  unsigned short* wfrag  = (unsigned short*)(base + 256);         // 49152 B
  unsigned short* wp_bf  = (unsigned short*)(base + 256 + 49152); // 384 B (pad 512)
  float*          biases = (float*)(base + 256 + 49152 + 512);    // 2816 B

  Ptrs ptrs;
  for (int i = 0; i < 21; i++){ ptrs.p[i] = d_in[i]; ptrs.n[i] = in_sizes[i]; }
  PrepPtrs pp;
  pp.w[0] = d_in[3];  pp.w[1] = d_in[5];  pp.w[2] = d_in[7];
  pp.w[3] = d_in[13]; pp.w[4] = d_in[17]; pp.w[5] = d_in[19];
  pp.wp = d_in[9];
  pp.b[0] = d_in[4];  pp.b[1] = d_in[6];  pp.b[2] = d_in[8];  pp.b[3] = d_in[10];
  pp.b[4] = d_in[11]; pp.b[5] = d_in[12]; pp.b[6] = d_in[14]; pp.b[7] = d_in[15];
  pp.b[8] = d_in[16]; pp.b[9] = d_in[18]; pp.b[10] = d_in[20];

  detect_kernel<<<6, 256, 0, stream>>>(ptrs, flags);
  prep_kernel<<<32, 256, 0, stream>>>(pp, flags, wfrag, wp_bf, biases);
  qkv_kernel<<<512, 256, 0, stream>>>(d_in[1], wfrag, biases, q_ws, k_ws, v_ws, flags, N);
  pt_kernel<<<1024, 256, 0, stream>>>(d_in[0], d_in[1], (const int*)d_in[2], q_ws, k_ws, v_ws,
                                      wfrag, wp_bf, biases, flags, d_out, N);
}